// Round 11
// baseline (204.449 us; speedup 1.0000x reference)
//
#include <hip/hip_runtime.h>

typedef unsigned short ushort_t;
typedef __attribute__((ext_vector_type(8))) short bf16x8;
typedef __attribute__((ext_vector_type(8))) unsigned short u16x8;
typedef __attribute__((ext_vector_type(4))) float f32x4;

#define B_ 64
#define N_ 1024
#define C_ 128

static __device__ __forceinline__ unsigned short f2bf(float f) {  // RNE
  union { float f; unsigned int i; } v; v.f = f;
  unsigned int i = v.i;
  return (unsigned short)((i + 0x7FFFu + ((i >> 16) & 1u)) >> 16);
}
// truncation split: x = hi + lo + eps, |eps| <= 2^-17 |x|
static __device__ __forceinline__ void split1(float x, ushort_t& h, ushort_t& l) {
  union { float f; unsigned int i; } u; u.f = x;
  h = (ushort_t)(u.i >> 16);
  union { unsigned int i; float f; } t; t.i = u.i & 0xFFFF0000u;
  union { float f; unsigned int i; } w; w.f = x - t.f;
  l = (ushort_t)(w.i >> 16);
}
static __device__ __forceinline__ bf16x8 as_bf(u16x8 v) {
  union { u16x8 u; bf16x8 b; } x; x.u = v; return x.b;
}
static __device__ __forceinline__ void gload_lds16(const void* g, void* l) {
  __builtin_amdgcn_global_load_lds((const __attribute__((address_space(1))) void*)g,
                                   (__attribute__((address_space(3))) void*)l,
                                   16, 0, 0);
}

// ---------------------------------------------------------------------------
// Transpose + split: src fp32 [rows][cols] -> dh/dl bf16 [cols][rows]
// ---------------------------------------------------------------------------
__global__ __launch_bounds__(256) void tsplit(const float* __restrict__ src,
                                              ushort_t* __restrict__ dh,
                                              ushort_t* __restrict__ dl,
                                              int rows, int cols, long sb, long db) {
  __shared__ float tile[64][65];
  const int t = threadIdx.x;
  src += (long)blockIdx.z * sb;
  dh  += (long)blockIdx.z * db;
  dl  += (long)blockIdx.z * db;
  const int r0 = blockIdx.y * 64, c0 = blockIdx.x * 64;
#pragma unroll
  for (int p = 0; p < 4; ++p) {
    int row = p * 16 + (t >> 4), c4 = (t & 15) * 4;
    f32x4 v = *(const f32x4*)(src + (long)(r0 + row) * cols + c0 + c4);
#pragma unroll
    for (int j = 0; j < 4; ++j) tile[row][c4 + j] = v[j];
  }
  __syncthreads();
  const int oc = t >> 2;
#pragma unroll
  for (int p = 0; p < 2; ++p) {
    int ck = (t & 3) + p * 4;
    u16x8 vh, vl;
#pragma unroll
    for (int j = 0; j < 8; ++j) {
      ushort_t hj, lj;
      split1(tile[ck * 8 + j][oc], hj, lj);
      vh[j] = hj; vl[j] = lj;
    }
    long o = (long)(c0 + oc) * rows + r0 + ck * 8;
    *(u16x8*)(dh + o) = vh;
    *(u16x8*)(dl + o) = vl;
  }
}

// ---------------------------------------------------------------------------
// GC GEMM — 512-thread / 8-wave blocks -> 4 waves/SIMD (the TLP the pipe-
// utilization model demands). v = adj[b] @ ann[b] + bias -> vbuf (fp32).
// Wave grid 2x4: wave tile 64 rows x 32 cols, acc[4][2] (32 VGPR).
// BK=32, 32 steps, double-buffered LDS (64 KB total -> 2 blocks/CU):
//   A: adj fp32 flat-loaded 2 steps ahead into regs (8 el/thread), split
//      hi/lo ONCE (cooperative, not per-wave), ds_write swizzled.
//   B: annT hi/lo via global_load_lds, source-swizzled, 1 step ahead.
// One __syncthreads per step: drains loads issued a full compute earlier.
// All LDS patterns 2-way bank aliasing (free): slot XOR ((row>>1)&3).
// ---------------------------------------------------------------------------
__global__ __launch_bounds__(512, 4) void gc_gemm(const float* __restrict__ adj,
                                                  const ushort_t* __restrict__ annTh,
                                                  const ushort_t* __restrict__ annTl,
                                                  const float* __restrict__ gcb,
                                                  float* __restrict__ vout) {
  __shared__ __align__(16) ushort_t ldsAh[2 * 4096];  // [buf][128][32] bf16, 16 KB
  __shared__ __align__(16) ushort_t ldsAl[2 * 4096];
  __shared__ __align__(16) ushort_t ldsBh[2 * 4096];
  __shared__ __align__(16) ushort_t ldsBl[2 * 4096];

  const int tid = threadIdx.x;
  const int w = tid >> 6, lane = tid & 63;
  const int wr = w >> 2, wc = w & 3;            // wave grid 2 x 4
  // XCD-chunked swizzle (grid=512, bijective)
  const int swz = (blockIdx.x & 7) * 64 + (blockIdx.x >> 3);
  const int b = swz >> 3;
  const int m0 = (swz & 7) * 128;

  const float*    adjb = adj   + ((long)b * N_ + m0) * N_;  // [128][1024] fp32
  const ushort_t* aThb = annTh + (long)b * C_ * N_;         // [128][1024] bf16
  const ushort_t* aTlb = annTl + (long)b * C_ * N_;

  const int fr = lane & 15;
  const int kg = lane >> 4;

  // staging maps: thread -> (row 0..127, slot 0..3); swizzled slot = ce ^ ((row>>1)&3)
  const int srow = tid >> 2;
  const int sce  = tid & 3;
  const int ssl  = sce ^ ((srow >> 1) & 3);
  const float*    aSrc  = adjb + (long)srow * N_ + sce * 8;   // A: global chunk sce
  const ushort_t* bSrcH = aThb + (long)srow * N_ + ssl * 8;   // B: pre-swizzled source
  const ushort_t* bSrcL = aTlb + (long)srow * N_ + ssl * 8;
  const int aDst = srow * 32 + ssl * 8;                        // A ds_write offset (ushorts)

  f32x4 acc[4][2] = {};
  f32x4 A0_, A1_;   // A(t+1) data, 8 fp32/thread

#define LOADA(T)                                                               \
  { A0_ = *(const f32x4*)(aSrc + (T) * 32); A1_ = *(const f32x4*)(aSrc + (T) * 32 + 4); }

#define SPLITWRITE(BUF)                                                        \
  {                                                                            \
    u16x8 vh_, vl_;                                                            \
    _Pragma("unroll")                                                          \
    for (int j = 0; j < 4; ++j) {                                              \
      ushort_t hj_, lj_;                                                       \
      split1(A0_[j], hj_, lj_); vh_[j] = hj_;     vl_[j] = lj_;                \
      split1(A1_[j], hj_, lj_); vh_[4 + j] = hj_; vl_[4 + j] = lj_;            \
    }                                                                          \
    *(u16x8*)&ldsAh[(BUF) * 4096 + aDst] = vh_;                                \
    *(u16x8*)&ldsAl[(BUF) * 4096 + aDst] = vl_;                                \
  }

#define GLOADB(BUF, T)                                                         \
  {                                                                            \
    gload_lds16(bSrcH + (T) * 32, (void*)(ldsBh + (BUF) * 4096 + tid * 8));    \
    gload_lds16(bSrcL + (T) * 32, (void*)(ldsBl + (BUF) * 4096 + tid * 8));    \
  }

#define COMPUTE(BUF)                                                           \
  {                                                                            \
    bf16x8 ah_[4], al_[4];                                                     \
    _Pragma("unroll")                                                          \
    for (int mi = 0; mi < 4; ++mi) {                                           \
      int row_ = wr * 64 + mi * 16 + fr;                                       \
      int off_ = row_ * 32 + (kg ^ ((row_ >> 1) & 3)) * 8;                     \
      ah_[mi] = *(const bf16x8*)&ldsAh[(BUF) * 4096 + off_];                   \
      al_[mi] = *(const bf16x8*)&ldsAl[(BUF) * 4096 + off_];                   \
    }                                                                          \
    _Pragma("unroll")                                                          \
    for (int ni = 0; ni < 2; ++ni) {                                           \
      int rb_ = wc * 32 + ni * 16 + fr;                                        \
      int ob_ = rb_ * 32 + (kg ^ ((rb_ >> 1) & 3)) * 8;                        \
      bf16x8 bh_ = *(const bf16x8*)&ldsBh[(BUF) * 4096 + ob_];                 \
      bf16x8 bl_ = *(const bf16x8*)&ldsBl[(BUF) * 4096 + ob_];                 \
      _Pragma("unroll")                                                        \
      for (int mi = 0; mi < 4; ++mi) {                                         \
        acc[mi][ni] = __builtin_amdgcn_mfma_f32_16x16x32_bf16(ah_[mi], bh_, acc[mi][ni], 0, 0, 0); \
        acc[mi][ni] = __builtin_amdgcn_mfma_f32_16x16x32_bf16(al_[mi], bh_, acc[mi][ni], 0, 0, 0); \
        acc[mi][ni] = __builtin_amdgcn_mfma_f32_16x16x32_bf16(ah_[mi], bl_, acc[mi][ni], 0, 0, 0); \
      }                                                                        \
    }                                                                          \
  }

  // prologue: A(0)+B(0) into buf0; preload A(1)
  LOADA(0)
  SPLITWRITE(0)
  GLOADB(0, 0)
  LOADA(1)
  __syncthreads();

#pragma unroll 1
  for (int t = 0; t < 32; ++t) {
    const int cur = t & 1;
    if (t < 31) {                    // stage t+1 into buf^1 (free since t-1)
      SPLITWRITE(cur ^ 1)            // split+write A(t+1) (regs loaded at t-1)
      GLOADB(cur ^ 1, t + 1)         // B(t+1) direct-to-LDS
    }
    if (t < 30) { LOADA(t + 2) }     // A(t+2) flat loads, in flight over compute
    COMPUTE(cur)
    __syncthreads();                 // drains this step's issues; reuse guard
  }

#undef LOADA
#undef SPLITWRITE
#undef GLOADB
#undef COMPUTE

  const long rowbase = (long)b * N_ + m0 + wr * 64;
#pragma unroll
  for (int ni = 0; ni < 2; ++ni) {
    int col = wc * 32 + ni * 16 + fr;
    float bias = gcb[col];
#pragma unroll
    for (int mi = 0; mi < 4; ++mi)
#pragma unroll
      for (int r = 0; r < 4; ++r)
        vout[(rowbase + mi * 16 + kg * 4 + r) * C_ + col] = acc[mi][ni][r] + bias;
  }
}

// ---------------------------------------------------------------------------
// GRU single step, software-pipelined weight streaming (r8 verbatim).
// ---------------------------------------------------------------------------
__global__ __launch_bounds__(256, 2) void gru(const float* __restrict__ v,
                                              const float* __restrict__ ann,
                                              const ushort_t* __restrict__ kTh,
                                              const ushort_t* __restrict__ kTl,
                                              const ushort_t* __restrict__ rTh,
                                              const float* __restrict__ gb,
                                              float* __restrict__ out) {
  const int w = threadIdx.x >> 6, lane = threadIdx.x & 63;
  const long m0 = ((long)blockIdx.x * 4 + w) * 32;
  const int fr = lane & 15, kg = lane >> 4;

  bf16x8 xh[2][4], xl[2][4], hh[2][4];
#pragma unroll
  for (int s = 0; s < 2; ++s)
#pragma unroll
    for (int kk = 0; kk < 4; ++kk) {
      long off = (m0 + s * 16 + fr) * (long)C_ + kk * 32 + kg * 8;
      f32x4 x0 = *(const f32x4*)(v + off);
      f32x4 x1 = *(const f32x4*)(v + off + 4);
      u16x8 th, tl;
#pragma unroll
      for (int j = 0; j < 4; ++j) {
        ushort_t hj, lj;
        split1(x0[j], hj, lj); th[j] = hj; tl[j] = lj;
        split1(x1[j], hj, lj); th[4 + j] = hj; tl[4 + j] = lj;
      }
      xh[s][kk] = as_bf(th); xl[s][kk] = as_bf(tl);
      f32x4 h0 = *(const f32x4*)(ann + off);
      f32x4 h1 = *(const f32x4*)(ann + off + 4);
      u16x8 hv;
#pragma unroll
      for (int j = 0; j < 4; ++j) { hv[j] = f2bf(h0[j]); hv[4 + j] = f2bf(h1[j]); }
      hh[s][kk] = as_bf(hv);
    }

  bf16x8 W0K[4], W0L[4], W0R[4], W1K[4], W1L[4], W1R[4];
  float HV0[8], HV1[8];

#define LOADW(WK, WL, WR, NN, GG)                                              \
  {                                                                            \
    const ushort_t* kh_ = kTh + (long)((GG) * C_ + (NN) * 16 + fr) * C_;       \
    const ushort_t* kl_ = kTl + (long)((GG) * C_ + (NN) * 16 + fr) * C_;       \
    const ushort_t* rh_ = rTh + (long)((GG) * C_ + (NN) * 16 + fr) * C_;       \
    _Pragma("unroll")                                                          \
    for (int kk = 0; kk < 4; ++kk) {                                           \
      int o_ = kk * 32 + kg * 8;                                               \
      WK[kk] = *(const bf16x8*)(kh_ + o_);                                     \
      WL[kk] = *(const bf16x8*)(kl_ + o_);                                     \
      WR[kk] = *(const bf16x8*)(rh_ + o_);                                     \
    }                                                                          \
  }

#define LOADHV(HV, NN)                                                         \
  _Pragma("unroll")                                                            \
  for (int s = 0; s < 2; ++s)                                                  \
    _Pragma("unroll")                                                          \
    for (int r = 0; r < 4; ++r)                                                \
      HV[s * 4 + r] = ann[(m0 + s * 16 + kg * 4 + r) * (long)C_ + (NN) * 16 + fr];

#define MATH(WK, WL, WR, AK0, AK1, AR0, AR1)                                   \
  {                                                                            \
    _Pragma("unroll")                                                          \
    for (int kk = 0; kk < 4; ++kk) {                                           \
      AK0 = __builtin_amdgcn_mfma_f32_16x16x32_bf16(xh[0][kk], WK[kk], AK0, 0, 0, 0); \
      AK1 = __builtin_amdgcn_mfma_f32_16x16x32_bf16(xh[1][kk], WK[kk], AK1, 0, 0, 0); \
      AK0 = __builtin_amdgcn_mfma_f32_16x16x32_bf16(xl[0][kk], WK[kk], AK0, 0, 0, 0); \
      AK1 = __builtin_amdgcn_mfma_f32_16x16x32_bf16(xl[1][kk], WK[kk], AK1, 0, 0, 0); \
      AK0 = __builtin_amdgcn_mfma_f32_16x16x32_bf16(xh[0][kk], WL[kk], AK0, 0, 0, 0); \
      AK1 = __builtin_amdgcn_mfma_f32_16x16x32_bf16(xh[1][kk], WL[kk], AK1, 0, 0, 0); \
    }                                                                          \
    _Pragma("unroll")                                                          \
    for (int kk = 0; kk < 4; ++kk) {                                           \
      AR0 = __builtin_amdgcn_mfma_f32_16x16x32_bf16(hh[0][kk], WR[kk], AR0, 0, 0, 0); \
      AR1 = __builtin_amdgcn_mfma_f32_16x16x32_bf16(hh[1][kk], WR[kk], AR1, 0, 0, 0); \
    }                                                                          \
  }

#define EPILOGUE(NN, HV)                                                       \
  {                                                                            \
    const int cb = (NN) * 16 + fr;                                             \
    const float bz  = gb[cb] + gb[384 + cb];                                   \
    const float brr = gb[128 + cb] + gb[384 + 128 + cb];                       \
    const float bxh = gb[256 + cb];                                            \
    const float bhi = gb[384 + 256 + cb];                                      \
    _Pragma("unroll")                                                          \
    for (int s = 0; s < 2; ++s) {                                              \
      const f32x4& az_ = s ? az1 : az0;                                        \
      const f32x4& ar_ = s ? ar1 : ar0;                                        \
      const f32x4& ax_ = s ? ax1 : ax0;                                        \
      const f32x4& ah_ = s ? ah1 : ah0;                                        \
      _Pragma("unroll")                                                        \
      for (int r = 0; r < 4; ++r) {                                            \
        long row = m0 + s * 16 + kg * 4 + r;                                   \
        float hval = HV[s * 4 + r];                                            \
        float zz = 1.f / (1.f + __expf(-(az_[r] + bz)));                       \
        float rr = 1.f / (1.f + __expf(-(ar_[r] + brr)));                      \
        float hpre = ax_[r] + bxh + rr * (ah_[r] + bhi);                       \
        hpre = fminf(fmaxf(hpre, -15.f), 15.f);                                \
        float e2 = __expf(2.f * hpre);                                         \
        float th = (e2 - 1.f) / (e2 + 1.f);                                    \
        out[row * C_ + cb] = zz * hval + (1.f - zz) * th;                      \
      }                                                                        \
    }                                                                          \
  }

  LOADW(W0K, W0L, W0R, 0, 0)
  LOADHV(HV0, 0)

#pragma unroll 1
  for (int n = 0; n < 8; n += 2) {
    {
      f32x4 az0 = {}, az1 = {}, ar0 = {}, ar1 = {}, ax0 = {}, ax1 = {}, ah0 = {}, ah1 = {};
      LOADW(W1K, W1L, W1R, n, 1)
      MATH(W0K, W0L, W0R, az0, az1, az0, az1)
      LOADW(W0K, W0L, W0R, n, 2)
      MATH(W1K, W1L, W1R, ar0, ar1, ar0, ar1)
      LOADW(W1K, W1L, W1R, n + 1, 0)
      LOADHV(HV1, n + 1)
      MATH(W0K, W0L, W0R, ax0, ax1, ah0, ah1)
      EPILOGUE(n, HV0)
    }
    {
      f32x4 az0 = {}, az1 = {}, ar0 = {}, ar1 = {}, ax0 = {}, ax1 = {}, ah0 = {}, ah1 = {};
      LOADW(W0K, W0L, W0R, n + 1, 1)
      MATH(W1K, W1L, W1R, az0, az1, az0, az1)
      LOADW(W1K, W1L, W1R, n + 1, 2)
      MATH(W0K, W0L, W0R, ar0, ar1, ar0, ar1)
      const int nn2 = (n + 2 < 8) ? (n + 2) : 0;  // dummy-safe prefetch
      LOADW(W0K, W0L, W0R, nn2, 0)
      LOADHV(HV0, nn2)
      MATH(W1K, W1L, W1R, ax0, ax1, ah0, ah1)
      EPILOGUE(n + 1, HV1)
    }
  }
#undef LOADW
#undef LOADHV
#undef MATH
#undef EPILOGUE
}

// ---------------------------------------------------------------------------
extern "C" void kernel_launch(void* const* d_in, const int* in_sizes, int n_in,
                              void* d_out, int out_size, void* d_ws, size_t ws_size,
                              hipStream_t stream) {
  const float* adj = (const float*)d_in[0];
  const float* ann = (const float*)d_in[1];
  const float* gcb = (const float*)d_in[2];
  const float* ker = (const float*)d_in[3];
  const float* rk  = (const float*)d_in[4];
  const float* gb  = (const float*)d_in[5];
  float* out = (float*)d_out;

  char* ws = (char*)d_ws;
  ushort_t* annTh = (ushort_t*)(ws);                      // [64][128][1024] bf16, 16 MB
  ushort_t* annTl = (ushort_t*)(ws + 16777216);           // 16 MB
  ushort_t* kTh   = (ushort_t*)(ws + 33554432);           // [384][128]
  ushort_t* kTl   = (ushort_t*)(ws + 33652736);
  ushort_t* rTh   = (ushort_t*)(ws + 33751040);
  ushort_t* rTl   = (ushort_t*)(ws + 33849344);
  float*    vbuf  = (float*)(ws + 33947648);              // [65536][128] fp32, 33.5 MB

  // ann [b][1024][128] -> annT hi/lo [b][128][1024]
  hipLaunchKernelGGL(tsplit, dim3(2, 16, 64), dim3(256), 0, stream,
                     ann, annTh, annTl, 1024, 128, (long)1024 * 128, (long)128 * 1024);
  // kernel/recurrent [128][384] -> [384][128] hi/lo
  hipLaunchKernelGGL(tsplit, dim3(6, 2, 1), dim3(256), 0, stream,
                     ker, kTh, kTl, 128, 384, 0L, 0L);
  hipLaunchKernelGGL(tsplit, dim3(6, 2, 1), dim3(256), 0, stream,
                     rk, rTh, rTl, 128, 384, 0L, 0L);
  // graph convolution -> vbuf (512-thread / 8-wave blocks)
  hipLaunchKernelGGL(gc_gemm, dim3(512), dim3(512), 0, stream,
                     adj, annTh, annTl, gcb, vbuf);
  // GRU step
  hipLaunchKernelGGL(gru, dim3(512), dim3(256), 0, stream,
                     vbuf, ann, kTh, kTl, rTh, gb, out);
}

// Round 12
// 163.817 us; speedup vs baseline: 1.2480x; 1.2480x over previous
//
#include <hip/hip_runtime.h>

typedef unsigned short ushort_t;
typedef __attribute__((ext_vector_type(8))) short bf16x8;
typedef __attribute__((ext_vector_type(8))) unsigned short u16x8;
typedef __attribute__((ext_vector_type(4))) float f32x4;

#define B_ 64
#define N_ 1024
#define C_ 128

static __device__ __forceinline__ unsigned short f2bf(float f) {  // RNE
  union { float f; unsigned int i; } v; v.f = f;
  unsigned int i = v.i;
  return (unsigned short)((i + 0x7FFFu + ((i >> 16) & 1u)) >> 16);
}
// truncation split: x = hi + lo + eps, |eps| <= 2^-17 |x|
static __device__ __forceinline__ void split1(float x, ushort_t& h, ushort_t& l) {
  union { float f; unsigned int i; } u; u.f = x;
  h = (ushort_t)(u.i >> 16);
  union { unsigned int i; float f; } t; t.i = u.i & 0xFFFF0000u;
  union { float f; unsigned int i; } w; w.f = x - t.f;
  l = (ushort_t)(w.i >> 16);
}
static __device__ __forceinline__ bf16x8 as_bf(u16x8 v) {
  union { u16x8 u; bf16x8 b; } x; x.u = v; return x.b;
}
static __device__ __forceinline__ void gload_lds16(const void* g, void* l) {
  __builtin_amdgcn_global_load_lds((const __attribute__((address_space(1))) void*)g,
                                   (__attribute__((address_space(3))) void*)l,
                                   16, 0, 0);
}

// T4 counted-wait barrier: leave N VMEM ops in flight across the barrier.
#define PIPE_BAR(N) asm volatile("s_waitcnt vmcnt(" #N ")\n\ts_barrier" ::: "memory")
// post-compute reuse guard (no vmcnt drain)
#define POST_BAR()  asm volatile("s_waitcnt lgkmcnt(0)\n\ts_barrier" ::: "memory")

// ---------------------------------------------------------------------------
// Transpose + split: src fp32 [rows][cols] -> dh/dl bf16 [cols][rows]
// ---------------------------------------------------------------------------
__global__ __launch_bounds__(256) void tsplit(const float* __restrict__ src,
                                              ushort_t* __restrict__ dh,
                                              ushort_t* __restrict__ dl,
                                              int rows, int cols, long sb, long db) {
  __shared__ float tile[64][65];
  const int t = threadIdx.x;
  src += (long)blockIdx.z * sb;
  dh  += (long)blockIdx.z * db;
  dl  += (long)blockIdx.z * db;
  const int r0 = blockIdx.y * 64, c0 = blockIdx.x * 64;
#pragma unroll
  for (int p = 0; p < 4; ++p) {
    int row = p * 16 + (t >> 4), c4 = (t & 15) * 4;
    f32x4 v = *(const f32x4*)(src + (long)(r0 + row) * cols + c0 + c4);
#pragma unroll
    for (int j = 0; j < 4; ++j) tile[row][c4 + j] = v[j];
  }
  __syncthreads();
  const int oc = t >> 2;
#pragma unroll
  for (int p = 0; p < 2; ++p) {
    int ck = (t & 3) + p * 4;
    u16x8 vh, vl;
#pragma unroll
    for (int j = 0; j < 8; ++j) {
      ushort_t hj, lj;
      split1(tile[ck * 8 + j][oc], hj, lj);
      vh[j] = hj; vl[j] = lj;
    }
    long o = (long)(c0 + oc) * rows + r0 + ck * 8;
    *(u16x8*)(dh + o) = vh;
    *(u16x8*)(dl + o) = vl;
  }
}

// ---------------------------------------------------------------------------
// Fused GC GEMM + GRU — depth-1 counted-vmcnt pipeline at 2 blocks/CU.
// GC: 128x128 tile, 4 waves (2x2), BK=32, 32 steps. All K-loop VMEM is
//   global_load_lds (8/wave/step). 2 staging buffers x 32 KB inside vlds
//   (67.6 KB total -> 2 blocks/CU = 2 independent barrier contexts).
//   Per step: STAGE(buf^1, t+1); vmcnt(8)+barrier  [waits stage(t), issued a
//   full step earlier -> ~zero residual; stage(t+1) stays in flight];
//   COMPUTE(buf); lgkmcnt(0)+barrier. Macros/swizzles verbatim from r10
//   (on-device verified, absmax 0.03125).
// GRU: fused r3 tail (handoff via vlds, weights streamed from L2).
// ---------------------------------------------------------------------------
__global__ __launch_bounds__(256, 2) void gc_gru(const float* __restrict__ adj,
                                                 const ushort_t* __restrict__ annTh,
                                                 const ushort_t* __restrict__ annTl,
                                                 const float* __restrict__ ann,
                                                 const float* __restrict__ gcb,
                                                 const ushort_t* __restrict__ kTh,
                                                 const ushort_t* __restrict__ kTl,
                                                 const ushort_t* __restrict__ rTh,
                                                 const float* __restrict__ gb,
                                                 float* __restrict__ out) {
  __shared__ __align__(16) float vlds[128 * 132];   // 67.6 KB; staging uses 64 KB
  // buffer q: A fp32 [128][32] @ q*32KB; Bh bf16 @ +16KB; Bl bf16 @ +24KB
  float* lds_all = vlds;

  const int tid = threadIdx.x;
  const int w = tid >> 6, lane = tid & 63;
  const int wr = w >> 1, wc = w & 1;
  // XCD-chunked swizzle (grid=512, bijective)
  const int swz = (blockIdx.x & 7) * 64 + (blockIdx.x >> 3);
  const int b = swz >> 3;
  const int m0 = (swz & 7) * 128;

  const float*    adjb = adj   + ((long)b * N_ + m0) * N_;  // [128][1024] fp32
  const ushort_t* aThb = annTh + (long)b * C_ * N_;         // [128][1024] bf16
  const ushort_t* aTlb = annTl + (long)b * C_ * N_;

  const int fr = lane & 15;
  const int kg = lane >> 4;

  // staging source swizzles (inverse of read-side XOR; involutions) — r10 verbatim
  const int aRow = lane >> 3;                        // row within 8-row A inst
  const int aCs  = (lane & 7) ^ aRow;                // fp32x4-chunk source idx
  const int bRow = lane >> 2;                        // row within 16-row B inst
  const int bCs  = (lane & 3) ^ ((lane >> 3) & 3);   // 16B-slot source idx

  f32x4 acc[4][4] = {};

#define STAGE(Q, T)                                                            \
  {                                                                            \
    const int k0_ = (T) * 32;                                                  \
    float*    A_  = lds_all + (Q) * 8192;                                      \
    ushort_t* Bh_ = (ushort_t*)(lds_all + (Q) * 8192 + 4096);                  \
    ushort_t* Bl_ = (ushort_t*)(lds_all + (Q) * 8192 + 6144);                  \
    _Pragma("unroll")                                                          \
    for (int jj = 0; jj < 4; ++jj) {                                           \
      int j_ = w * 4 + jj;                                                     \
      gload_lds16(adjb + (long)(j_ * 8 + aRow) * N_ + k0_ + aCs * 4,           \
                  (void*)(A_ + j_ * 256));                                     \
    }                                                                          \
    _Pragma("unroll")                                                          \
    for (int jj = 0; jj < 2; ++jj) {                                           \
      int j_ = w * 2 + jj;                                                     \
      long so_ = (long)(j_ * 16 + bRow) * N_ + k0_ + bCs * 8;                  \
      gload_lds16(aThb + so_, (void*)(Bh_ + j_ * 512));                        \
      gload_lds16(aTlb + so_, (void*)(Bl_ + j_ * 512));                        \
    }                                                                          \
  }

#define COMPUTE(Q)                                                             \
  {                                                                            \
    const float*    A_  = lds_all + (Q) * 8192;                                \
    const ushort_t* Bh_ = (const ushort_t*)(lds_all + (Q) * 8192 + 4096);      \
    const ushort_t* Bl_ = (const ushort_t*)(lds_all + (Q) * 8192 + 6144);      \
    bf16x8 bh_[4], bl_[4], ah_[4], al_[4];                                     \
    _Pragma("unroll")                                                          \
    for (int ni = 0; ni < 4; ++ni) {                                           \
      int row_ = wc * 64 + ni * 16 + fr;                                       \
      int kb_ = (kg << 4) ^ ((((row_) >> 1) & 3) << 4);                        \
      bh_[ni] = *(const bf16x8*)((const char*)Bh_ + row_ * 64 + kb_);          \
      bl_[ni] = *(const bf16x8*)((const char*)Bl_ + row_ * 64 + kb_);          \
    }                                                                          \
    _Pragma("unroll")                                                          \
    for (int mi = 0; mi < 4; ++mi) {                                           \
      int row_ = wr * 64 + mi * 16 + fr;                                       \
      int b0_ = row_ * 128 + ((kg * 32) ^ ((row_ & 7) << 4));                  \
      f32x4 a0_ = *(const f32x4*)((const char*)A_ + b0_);                      \
      f32x4 a1_ = *(const f32x4*)((const char*)A_ + (b0_ ^ 16));               \
      u16x8 vh_, vl_;                                                          \
      _Pragma("unroll")                                                        \
      for (int j = 0; j < 4; ++j) {                                            \
        ushort_t hj_, lj_;                                                     \
        split1(a0_[j], hj_, lj_); vh_[j] = hj_;     vl_[j] = lj_;              \
        split1(a1_[j], hj_, lj_); vh_[4 + j] = hj_; vl_[4 + j] = lj_;          \
      }                                                                        \
      ah_[mi] = as_bf(vh_); al_[mi] = as_bf(vl_);                              \
    }                                                                          \
    _Pragma("unroll")                                                          \
    for (int mi = 0; mi < 4; ++mi)                                             \
      _Pragma("unroll")                                                        \
      for (int ni = 0; ni < 4; ++ni) {                                         \
        acc[mi][ni] = __builtin_amdgcn_mfma_f32_16x16x32_bf16(ah_[mi], bh_[ni], acc[mi][ni], 0, 0, 0); \
        acc[mi][ni] = __builtin_amdgcn_mfma_f32_16x16x32_bf16(al_[mi], bh_[ni], acc[mi][ni], 0, 0, 0); \
        acc[mi][ni] = __builtin_amdgcn_mfma_f32_16x16x32_bf16(ah_[mi], bl_[ni], acc[mi][ni], 0, 0, 0); \
      }                                                                        \
  }

  // prologue: stage(0) into buf0
  STAGE(0, 0)

#pragma unroll 1
  for (int t = 0; t < 31; ++t) {
    const int cur = t & 1;
    STAGE(cur ^ 1, t + 1)  // issue next tile: stays in flight across barrier
    PIPE_BAR(8);           // wait stage(t) (issued one full step ago), not t+1
    COMPUTE(cur)
    POST_BAR();            // ds_reads done -> buf(cur) reusable next step
  }
  PIPE_BAR(0);             // final tile (t=31, buf1): drain fully
  COMPUTE(1)
  __syncthreads();

#undef STAGE
#undef COMPUTE

  // ---- handoff: v (=acc+bias) -> vlds fp32 [128][132] ----
#pragma unroll
  for (int ni = 0; ni < 4; ++ni) {
    int col = wc * 64 + ni * 16 + fr;
    float bias = gcb[col];
#pragma unroll
    for (int mi = 0; mi < 4; ++mi) {
      int row = wr * 64 + mi * 16 + kg * 4;
#pragma unroll
      for (int r = 0; r < 4; ++r)
        vlds[(row + r) * 132 + col] = acc[mi][ni][r] + bias;
    }
  }
  __syncthreads();

  // ---- GRU (r3 fused tail): wave w owns global rows [w*32, w*32+32) ----
  const long grow = (long)b * N_ + m0 + w * 32;

  bf16x8 xh[2][4], xl[2][4], hh[2][4];
#pragma unroll
  for (int s = 0; s < 2; ++s)
#pragma unroll
    for (int kk = 0; kk < 4; ++kk) {
      int lo = (w * 32 + s * 16 + fr) * 132 + kk * 32 + kg * 8;
      f32x4 x0 = *(const f32x4*)&vlds[lo];
      f32x4 x1 = *(const f32x4*)&vlds[lo + 4];
      u16x8 th, tl;
#pragma unroll
      for (int j = 0; j < 4; ++j) {
        ushort_t hj, lj;
        split1(x0[j], hj, lj); th[j] = hj; tl[j] = lj;
        split1(x1[j], hj, lj); th[4 + j] = hj; tl[4 + j] = lj;
      }
      xh[s][kk] = as_bf(th); xl[s][kk] = as_bf(tl);
      const float* hrow = ann + (grow + s * 16 + fr) * C_ + kk * 32 + kg * 8;
      f32x4 h0 = *(const f32x4*)hrow;
      f32x4 h1 = *(const f32x4*)(hrow + 4);
      u16x8 hv;
#pragma unroll
      for (int j = 0; j < 4; ++j) { hv[j] = f2bf(h0[j]); hv[4 + j] = f2bf(h1[j]); }
      hh[s][kk] = as_bf(hv);
    }

#define GATE(G, AK0, AK1, AR0, AR1)                                                         \
  do {                                                                                      \
    const ushort_t* kh_ = kTh + (long)((G) * C_ + cb) * C_;                                 \
    const ushort_t* kl_ = kTl + (long)((G) * C_ + cb) * C_;                                 \
    const ushort_t* rh_ = rTh + (long)((G) * C_ + cb) * C_;                                 \
    bf16x8 KH[4], KL[4], RH[4];                                                             \
    _Pragma("unroll")                                                                       \
    for (int kk = 0; kk < 4; ++kk) {                                                        \
      int o_ = kk * 32 + kg * 8;                                                            \
      KH[kk] = *(const bf16x8*)(kh_ + o_);                                                  \
      KL[kk] = *(const bf16x8*)(kl_ + o_);                                                  \
      RH[kk] = *(const bf16x8*)(rh_ + o_);                                                  \
    }                                                                                       \
    _Pragma("unroll")                                                                       \
    for (int kk = 0; kk < 4; ++kk) {                                                        \
      AK0 = __builtin_amdgcn_mfma_f32_16x16x32_bf16(xh[0][kk], KH[kk], AK0, 0, 0, 0);       \
      AK1 = __builtin_amdgcn_mfma_f32_16x16x32_bf16(xh[1][kk], KH[kk], AK1, 0, 0, 0);       \
      AK0 = __builtin_amdgcn_mfma_f32_16x16x32_bf16(xl[0][kk], KH[kk], AK0, 0, 0, 0);       \
      AK1 = __builtin_amdgcn_mfma_f32_16x16x32_bf16(xl[1][kk], KH[kk], AK1, 0, 0, 0);       \
      AK0 = __builtin_amdgcn_mfma_f32_16x16x32_bf16(xh[0][kk], KL[kk], AK0, 0, 0, 0);       \
      AK1 = __builtin_amdgcn_mfma_f32_16x16x32_bf16(xh[1][kk], KL[kk], AK1, 0, 0, 0);       \
    }                                                                                       \
    _Pragma("unroll")                                                                       \
    for (int kk = 0; kk < 4; ++kk) {                                                        \
      AR0 = __builtin_amdgcn_mfma_f32_16x16x32_bf16(hh[0][kk], RH[kk], AR0, 0, 0, 0);       \
      AR1 = __builtin_amdgcn_mfma_f32_16x16x32_bf16(hh[1][kk], RH[kk], AR1, 0, 0, 0);       \
    }                                                                                       \
  } while (0)

#pragma unroll 1
  for (int n = 0; n < 8; ++n) {
    const int cb = n * 16 + fr;
    f32x4 az0 = {}, az1 = {}, ar0 = {}, ar1 = {}, ax0 = {}, ax1 = {}, ah0 = {}, ah1 = {};
    GATE(0, az0, az1, az0, az1);
    GATE(1, ar0, ar1, ar0, ar1);
    GATE(2, ax0, ax1, ah0, ah1);

    const float bz  = gb[cb] + gb[384 + cb];
    const float brr = gb[128 + cb] + gb[384 + 128 + cb];
    const float bxh = gb[256 + cb];
    const float bhi = gb[384 + 256 + cb];
#pragma unroll
    for (int s = 0; s < 2; ++s) {
      const f32x4& az_ = s ? az1 : az0;
      const f32x4& ar_ = s ? ar1 : ar0;
      const f32x4& ax_ = s ? ax1 : ax0;
      const f32x4& ah_ = s ? ah1 : ah0;
#pragma unroll
      for (int r = 0; r < 4; ++r) {
        long row = grow + s * 16 + kg * 4 + r;
        float hval = ann[row * C_ + cb];
        float zz = 1.f / (1.f + __expf(-(az_[r] + bz)));
        float rr = 1.f / (1.f + __expf(-(ar_[r] + brr)));
        float hpre = ax_[r] + bxh + rr * (ah_[r] + bhi);
        hpre = fminf(fmaxf(hpre, -15.f), 15.f);
        float e2 = __expf(2.f * hpre);
        float th = (e2 - 1.f) / (e2 + 1.f);
        out[row * C_ + cb] = zz * hval + (1.f - zz) * th;
      }
    }
  }
#undef GATE
}

// ---------------------------------------------------------------------------
extern "C" void kernel_launch(void* const* d_in, const int* in_sizes, int n_in,
                              void* d_out, int out_size, void* d_ws, size_t ws_size,
                              hipStream_t stream) {
  const float* adj = (const float*)d_in[0];
  const float* ann = (const float*)d_in[1];
  const float* gcb = (const float*)d_in[2];
  const float* ker = (const float*)d_in[3];
  const float* rk  = (const float*)d_in[4];
  const float* gb  = (const float*)d_in[5];
  float* out = (float*)d_out;

  char* ws = (char*)d_ws;
  ushort_t* annTh = (ushort_t*)(ws);                      // [64][128][1024] bf16, 16 MB
  ushort_t* annTl = (ushort_t*)(ws + 16777216);           // 16 MB
  ushort_t* kTh   = (ushort_t*)(ws + 33554432);           // [384][128]
  ushort_t* kTl   = (ushort_t*)(ws + 33652736);
  ushort_t* rTh   = (ushort_t*)(ws + 33751040);
  ushort_t* rTl   = (ushort_t*)(ws + 33849344);

  // ann [b][1024][128] -> annT hi/lo [b][128][1024]
  hipLaunchKernelGGL(tsplit, dim3(2, 16, 64), dim3(256), 0, stream,
                     ann, annTh, annTl, 1024, 128, (long)1024 * 128, (long)128 * 1024);
  // kernel/recurrent [128][384] -> [384][128] hi/lo
  hipLaunchKernelGGL(tsplit, dim3(6, 2, 1), dim3(256), 0, stream,
                     ker, kTh, kTl, 128, 384, 0L, 0L);
  hipLaunchKernelGGL(tsplit, dim3(6, 2, 1), dim3(256), 0, stream,
                     rk, rTh, rTl, 128, 384, 0L, 0L);
  // fused pipelined graph-conv + GRU
  hipLaunchKernelGGL(gc_gru, dim3(512), dim3(256), 0, stream,
                     adj, annTh, annTl, ann, gcb, kTh, kTl, rTh, gb, out);
}